// Round 8
// baseline (278.921 us; speedup 1.0000x reference)
//
#include <hip/hip_runtime.h>
#include <cstdint>

typedef __bf16 bf16_t;
typedef __attribute__((ext_vector_type(8))) __bf16 bf16x8;
typedef __attribute__((ext_vector_type(4))) __bf16 bf16x4;
typedef __attribute__((ext_vector_type(4))) float f32x4;

#define AS1 __attribute__((address_space(1)))
#define AS3 __attribute__((address_space(3)))

// ---------------------------------------------------------------------------
// Merged projection GEMM (steps 3+4 in ONE dispatch, 1536 blocks):
//   id <  1024 : QK[8192,2048] = Xb[8192,1024] @ WT_qk^T   (tile id: 64x16)
//   id >= 1024 : VT[1024,8192] = WvT[1024,1024] @ Xb^T     (tile id: 8x64)
// Both are NT bf16 GEMMs, K=1024, tile 128x128, BK=64, 256 threads,
// DOUBLE-BUFFERED LDS (64KB, 2 blocks/CU): one barrier/iter, prefetch for
// tile k+1 issued right after it. 717 TF measured (round 7, step 3).
// Merging saves a dispatch gap and backfills step 3's tail with step 4.
//
// LDS layout: rows of 8 16B-chunks, chunk q of row r at slot q ^ (r&7)
// (XOR swizzle): per-row-contiguous global reads + conflict-free
// ds_read_b128 (measured SQ_LDS_BANK_CONFLICT = 0).
// ---------------------------------------------------------------------------
__global__ __launch_bounds__(256)
void gemm_proj(const bf16_t* __restrict__ Xb, const bf16_t* __restrict__ WT,
               bf16_t* __restrict__ QK, bf16_t* __restrict__ VT)
{
  int id = blockIdx.x;
  const bf16_t *A, *B;
  bf16_t* C;
  int ldc, m0, n0;
  if (id < 1024) {                 // step 3: QK = Xb @ [Wq|Wk]
    A = Xb; B = WT; C = QK; ldc = 2048;
    m0 = (id >> 4) * 128; n0 = (id & 15) * 128;
  } else {                         // step 4: VT = WvT @ Xb^T
    id -= 1024;
    A = WT + 2 * 1024 * 1024; B = Xb; C = VT; ldc = 8192;
    m0 = (id >> 6) * 128; n0 = (id & 63) * 128;
  }
  const int lda = 1024, ldb = 1024, K = 1024;

  __shared__ bf16_t As[2][128 * 64];  // 16KB each
  __shared__ bf16_t Bs[2][128 * 64];

  const int tid = threadIdx.x;
  const int wave = tid >> 6, lane = tid & 63;
  const int lm = lane & 15, qd = lane >> 4;
  const int wm = (wave >> 1) * 64, wn = (wave & 1) * 64;

  const int rowl = lane >> 3;           // 0..7
  const int q = (lane & 7) ^ rowl;      // swizzled chunk within row
  const bf16_t* Abase = A + (long)(m0 + wave * 8 + rowl) * lda + q * 8;
  const bf16_t* Bbase = B + (long)(n0 + wave * 8 + rowl) * ldb + q * 8;
  const int woff = wave * 512;

  auto stage = [&](int k0, int b) {
#pragma unroll
    for (int i = 0; i < 4; i++) {
      __builtin_amdgcn_global_load_lds((const AS1 void*)(Abase + (long)i * 32 * lda + k0),
                                       (AS3 void*)(As[b] + woff + i * 2048), 16, 0, 0);
      __builtin_amdgcn_global_load_lds((const AS1 void*)(Bbase + (long)i * 32 * ldb + k0),
                                       (AS3 void*)(Bs[b] + woff + i * 2048), 16, 0, 0);
    }
  };

  f32x4 acc[4][4] = {};

  stage(0, 0);
  int buf = 0;
  for (int k0 = 0; k0 < K; k0 += 64) {
    __syncthreads();                   // drains tile-k loads (issued 1 iter ago)
    if (k0 + 64 < K) stage(k0 + 64, buf ^ 1);
#pragma unroll
    for (int s = 0; s < 2; s++) {
      bf16x8 aF[4], bF[4];
#pragma unroll
      for (int i = 0; i < 4; i++) {
        const int r = wm + i * 16 + lm;
        aF[i] = *(const bf16x8*)&As[buf][r * 64 + (((s * 4 + qd) ^ (lm & 7)) << 3)];
      }
#pragma unroll
      for (int j = 0; j < 4; j++) {
        const int r = wn + j * 16 + lm;
        bF[j] = *(const bf16x8*)&Bs[buf][r * 64 + (((s * 4 + qd) ^ (lm & 7)) << 3)];
      }
#pragma unroll
      for (int i = 0; i < 4; i++)
#pragma unroll
        for (int j = 0; j < 4; j++)
          acc[i][j] = __builtin_amdgcn_mfma_f32_16x16x32_bf16(aF[i], bF[j], acc[i][j], 0, 0, 0);
    }
    buf ^= 1;
  }

#pragma unroll
  for (int i = 0; i < 4; i++) {
    const int row = m0 + wm + i * 16 + qd * 4;
#pragma unroll
    for (int j = 0; j < 4; j++) {
      const int col = n0 + wn + j * 16 + lm;
#pragma unroll
      for (int r = 0; r < 4; r++)
        C[(long)(row + r) * ldc + col] = (bf16_t)acc[i][j][r];
    }
  }
}

// ---------------------------------------------------------------------------
// Small-tile NT bf16 GEMM for the causal steps: tile 64x128, BK=64,
// 256 threads (wave w covers cols w*32..w*32+31, all 64 rows).
// DOUBLE-BUFFERED 48KB LDS -> 3 blocks/CU; causal grids supply 1088/1024
// active blocks (~4.25/CU) -> both prefetch-across-barrier AND enough TLP,
// with low tile-granularity imbalance (the round-4/6/7 ladder showed dbuf
// is worth ~1.5x per block and 64-row tiles fix the makespan stretch).
//
// Same XOR-swizzled LDS layout (slot = q ^ (row&7)), measured conflict-free.
//
// causalHalf: skip block if bn > bm>>1    (S = QK^T lower-triangle tiles)
// kLimit64:   Keff = min(K, ((bm>>1)+1)*128), bm flipped heavy-first
//             (PV truncation; row-uniform within a 64-row tile and equal to
//              softmax's zero-filled kend -> no uninitialized P reads).
// ---------------------------------------------------------------------------
template <typename OutT>
__global__ __launch_bounds__(256)
void gemm_nt64(const bf16_t* __restrict__ A, const bf16_t* __restrict__ B,
               OutT* __restrict__ C, int K, int lda, int ldb, int ldc,
               long sA, long sB, long sC, int causalHalf, int kLimit64)
{
  int bm = blockIdx.y;
  const int bn = blockIdx.x;
  if (kLimit64) bm = gridDim.y - 1 - bm;   // heavy tiles dispatch first
  if (causalHalf && bn > (bm >> 1)) return;
  A += (long)blockIdx.z * sA;
  B += (long)blockIdx.z * sB;
  C += (long)blockIdx.z * sC;
  const int m0 = bm * 64, n0 = bn * 128;
  int Keff = K;
  if (kLimit64) { const int kl = ((bm >> 1) + 1) * 128; if (kl < Keff) Keff = kl; }

  __shared__ bf16_t As[2][64 * 64];    // 8KB each
  __shared__ bf16_t Bs[2][128 * 64];   // 16KB each  (48KB total)

  const int tid = threadIdx.x;
  const int wave = tid >> 6, lane = tid & 63;
  const int lm = lane & 15, qd = lane >> 4;
  const int wn = wave * 32;

  const int rowl = lane >> 3;           // 0..7
  const int q = (lane & 7) ^ rowl;      // swizzled chunk within row
  const bf16_t* Abase = A + (long)(m0 + wave * 8 + rowl) * lda + q * 8;
  const bf16_t* Bbase = B + (long)(n0 + wave * 8 + rowl) * ldb + q * 8;
  const int woff = wave * 512;          // wave-uniform LDS elem base

  auto stage = [&](int k0, int b) {
#pragma unroll
    for (int i = 0; i < 2; i++)
      __builtin_amdgcn_global_load_lds((const AS1 void*)(Abase + (long)i * 32 * lda + k0),
                                       (AS3 void*)(As[b] + woff + i * 2048), 16, 0, 0);
#pragma unroll
    for (int i = 0; i < 4; i++)
      __builtin_amdgcn_global_load_lds((const AS1 void*)(Bbase + (long)i * 32 * ldb + k0),
                                       (AS3 void*)(Bs[b] + woff + i * 2048), 16, 0, 0);
  };

  f32x4 acc[4][2] = {};

  stage(0, 0);
  int buf = 0;
  for (int k0 = 0; k0 < Keff; k0 += 64) {
    __syncthreads();                   // drains tile-k loads (issued 1 iter ago)
    if (k0 + 64 < Keff) stage(k0 + 64, buf ^ 1);
#pragma unroll
    for (int s = 0; s < 2; s++) {
      bf16x8 aF[4], bF[2];
#pragma unroll
      for (int i = 0; i < 4; i++) {
        const int r = i * 16 + lm;
        aF[i] = *(const bf16x8*)&As[buf][r * 64 + (((s * 4 + qd) ^ (lm & 7)) << 3)];
      }
#pragma unroll
      for (int j = 0; j < 2; j++) {
        const int r = wn + j * 16 + lm;
        bF[j] = *(const bf16x8*)&Bs[buf][r * 64 + (((s * 4 + qd) ^ (lm & 7)) << 3)];
      }
#pragma unroll
      for (int i = 0; i < 4; i++)
#pragma unroll
        for (int j = 0; j < 2; j++)
          acc[i][j] = __builtin_amdgcn_mfma_f32_16x16x32_bf16(aF[i], bF[j], acc[i][j], 0, 0, 0);
    }
    buf ^= 1;
  }

#pragma unroll
  for (int i = 0; i < 4; i++) {
    const int row = m0 + i * 16 + qd * 4;
#pragma unroll
    for (int j = 0; j < 2; j++) {
      const int col = n0 + wn + j * 16 + lm;
#pragma unroll
      for (int r = 0; r < 4; r++)
        C[(long)(row + r) * ldc + col] = (OutT)acc[i][j][r];
    }
  }
}

// ---------------------------------------------------------------------------
// fp32 -> bf16 elementwise (float4 in, bf16x4 out)
// ---------------------------------------------------------------------------
__global__ void cvt_f32_bf16(const float* __restrict__ in, bf16_t* __restrict__ out, int n4)
{
  const int i = blockIdx.x * blockDim.x + threadIdx.x;
  if (i >= n4) return;
  const float4 f = ((const float4*)in)[i];
  bf16x4 o = {(bf16_t)f.x, (bf16_t)f.y, (bf16_t)f.z, (bf16_t)f.w};
  ((bf16x4*)out)[i] = o;
}

// ---------------------------------------------------------------------------
// W [in=1024][out=1024] fp32  ->  WT [out][in] bf16, for z in {q,k,v}
// ---------------------------------------------------------------------------
__global__ void cvt_transpose_w(const float* __restrict__ wq, const float* __restrict__ wk,
                                const float* __restrict__ wv, bf16_t* __restrict__ WT)
{
  const float* W = (blockIdx.z == 0) ? wq : (blockIdx.z == 1) ? wk : wv;
  bf16_t* O = WT + (long)blockIdx.z * 1024 * 1024;
  __shared__ float tile[32][33];
  const int x = blockIdx.x * 32 + threadIdx.x;  // out dim (coalesced read)
  const int y = blockIdx.y * 32 + threadIdx.y;  // in dim
  tile[threadIdx.y][threadIdx.x] = W[(long)y * 1024 + x];
  __syncthreads();
  const int ox = blockIdx.x * 32 + threadIdx.y;  // out row
  const int oy = blockIdx.y * 32 + threadIdx.x;  // in col (coalesced write)
  O[(long)ox * 1024 + oy] = (bf16_t)tile[threadIdx.x][threadIdx.y];
}

// ---------------------------------------------------------------------------
// In-place causal softmax over S rows (bf16, ld=2048). One block per row.
// logits = S/32; writes P = softmax, zeros above the diagonal.
// Loads only j <= t; stores only j < kend = ((t>>7)+1)*128 — beyond kend P
// is never read by the PV GEMM (Keff stops there); [t+1, kend) gets zeros.
// ---------------------------------------------------------------------------
__global__ __launch_bounds__(256)
void softmax_causal(bf16_t* __restrict__ S)
{
  const int row = blockIdx.x;
  const int t = row & 2047;
  const int kend = ((t >> 7) + 1) << 7;
  bf16_t* Sr = S + (long)row * 2048;
  const int base = threadIdx.x * 8;

  uint4 u = {0, 0, 0, 0};
  if (base <= t) u = *(const uint4*)(Sr + base);
  const unsigned short* up = (const unsigned short*)&u;
  float v[8];
  float m = -3.0e38f;
#pragma unroll
  for (int j = 0; j < 8; j++) {
    const float x = __uint_as_float(((unsigned)up[j]) << 16);  // bf16 bits -> f32
    v[j] = (base + j <= t) ? x : -3.0e38f;
    m = fmaxf(m, v[j]);
  }
#pragma unroll
  for (int off = 32; off > 0; off >>= 1) m = fmaxf(m, __shfl_xor(m, off));
  __shared__ float redm[4], redl[4];
  const int wave = threadIdx.x >> 6, lane = threadIdx.x & 63;
  if (lane == 0) redm[wave] = m;
  __syncthreads();
  m = fmaxf(fmaxf(redm[0], redm[1]), fmaxf(redm[2], redm[3]));

  float p[8], l = 0.f;
#pragma unroll
  for (int j = 0; j < 8; j++) {
    p[j] = (base + j <= t) ? __expf((v[j] - m) * 0.03125f) : 0.f;
    l += p[j];
  }
#pragma unroll
  for (int off = 32; off > 0; off >>= 1) l += __shfl_xor(l, off);
  if (lane == 0) redl[wave] = l;
  __syncthreads();
  l = (redl[0] + redl[1]) + (redl[2] + redl[3]);
  const float rl = 1.0f / l;

  if (base < kend) {
    uint4 w;
    unsigned* wp = (unsigned*)&w;
#pragma unroll
    for (int h = 0; h < 4; h++) {
      bf16_t a = (bf16_t)(p[2 * h] * rl);
      bf16_t b = (bf16_t)(p[2 * h + 1] * rl);
      wp[h] = (unsigned)__builtin_bit_cast(unsigned short, a) |
              ((unsigned)__builtin_bit_cast(unsigned short, b) << 16);
    }
    *(uint4*)(Sr + base) = w;
  }
}

// ---------------------------------------------------------------------------
extern "C" void kernel_launch(void* const* d_in, const int* in_sizes, int n_in,
                              void* d_out, int out_size, void* d_ws, size_t ws_size,
                              hipStream_t stream)
{
  const float* X  = (const float*)d_in[0];  // [4,2048,1024]
  const float* Wq = (const float*)d_in[1];  // [1024,1024] (in,out)
  const float* Wk = (const float*)d_in[2];
  const float* Wv = (const float*)d_in[3];
  float* out = (float*)d_out;               // [4,2048,1024]

  // workspace layout (bytes): QK 33.5M | VT 16.8M | WT 6.3M | {Xb 16.8M / S 33.5M overlap}
  char* p = (char*)d_ws;
  bf16_t* QK = (bf16_t*)p;  p += (size_t)8192 * 2048 * 2;   // [8192, 2048]  Q|K
  bf16_t* VT = (bf16_t*)p;  p += (size_t)1024 * 8192 * 2;   // [1024, 8192]  V^T
  bf16_t* WT = (bf16_t*)p;  p += (size_t)3072 * 1024 * 2;   // [3072, 1024]  Wq^T|Wk^T|Wv^T
  bf16_t* Xb = (bf16_t*)p;                                  // [8192, 1024]  (dead before S)
  bf16_t* S  = (bf16_t*)p;                                  // [4][2048,2048] scores->P

  // 1) X -> bf16
  cvt_f32_bf16<<<8192, 256, 0, stream>>>(X, Xb, 8388608 / 4);
  // 2) W -> WT (bf16, transposed)
  cvt_transpose_w<<<dim3(32, 32, 3), dim3(32, 32), 0, stream>>>(Wq, Wk, Wv, WT);
  // 3+4) merged projections: QK = Xb@[Wq|Wk]  and  VT = WvT@Xb^T  (1536 blocks)
  gemm_proj<<<1536, 256, 0, stream>>>(Xb, WT, QK, VT);
  // 5) S = Q @ K^T per batch, 64-row tiles, lower-tri only (1088 active), dbuf
  gemm_nt64<bf16_t><<<dim3(16, 32, 4), 256, 0, stream>>>(
      QK, QK + 1024, S, 1024, 2048, 2048, 2048,
      (long)2048 * 2048, (long)2048 * 2048, (long)2048 * 2048, 1, 0);
  // 6) in-place causal softmax (truncated IO)
  softmax_causal<<<8192, 256, 0, stream>>>(S);
  // 7) O = P @ V (NT vs V^T), 64-row tiles, K truncated at diagonal, dbuf
  gemm_nt64<float><<<dim3(8, 32, 4), 256, 0, stream>>>(
      S, VT, out, 2048, 2048, 8192, 1024,
      (long)2048 * 2048, 2048, (long)2048 * 1024, 0, 1);
}

// Round 9
// 248.706 us; speedup vs baseline: 1.1215x; 1.1215x over previous
//
#include <hip/hip_runtime.h>
#include <cstdint>

typedef __bf16 bf16_t;
typedef __attribute__((ext_vector_type(8))) __bf16 bf16x8;
typedef __attribute__((ext_vector_type(4))) __bf16 bf16x4;
typedef __attribute__((ext_vector_type(4))) float f32x4;

#define AS1 __attribute__((address_space(1)))
#define AS3 __attribute__((address_space(3)))

// ---------------------------------------------------------------------------
// Big-tile NT bf16 GEMM: C[m,n] = sum_k A[m*lda+k] * B[n*ldb+k]
// Tile 128x128, BK=64, 256 threads, DOUBLE-BUFFERED LDS (64KB, 2 blocks/CU).
// One barrier/iter; prefetch for tile k+1 issued right after it. 717 TF
// measured (round 7, step 3). DO NOT merge multiple operand sets into this
// kernel (round 8: VGPR 88->132, MfmaUtil 28->20.5, -33% perf).
//
// LDS layout: rows of 8 16B-chunks, chunk q of row r at slot q ^ (r&7)
// (XOR swizzle): per-row-contiguous global reads + conflict-free
// ds_read_b128 (measured SQ_LDS_BANK_CONFLICT = 0).
// ---------------------------------------------------------------------------
template <typename OutT>
__global__ __launch_bounds__(256)
void gemm_nt(const bf16_t* __restrict__ A, const bf16_t* __restrict__ B,
             OutT* __restrict__ C, int K, int lda, int ldb, int ldc)
{
  const int bm = blockIdx.y, bn = blockIdx.x;
  const int m0 = bm * 128, n0 = bn * 128;

  __shared__ bf16_t As[2][128 * 64];  // 16KB each
  __shared__ bf16_t Bs[2][128 * 64];

  const int tid = threadIdx.x;
  const int wave = tid >> 6, lane = tid & 63;
  const int lm = lane & 15, qd = lane >> 4;
  const int wm = (wave >> 1) * 64, wn = (wave & 1) * 64;

  const int rowl = lane >> 3;           // 0..7
  const int q = (lane & 7) ^ rowl;      // swizzled chunk within row
  const bf16_t* Abase = A + (long)(m0 + wave * 8 + rowl) * lda + q * 8;
  const bf16_t* Bbase = B + (long)(n0 + wave * 8 + rowl) * ldb + q * 8;
  const int woff = wave * 512;

  auto stage = [&](int k0, int b) {
#pragma unroll
    for (int i = 0; i < 4; i++) {
      __builtin_amdgcn_global_load_lds((const AS1 void*)(Abase + (long)i * 32 * lda + k0),
                                       (AS3 void*)(As[b] + woff + i * 2048), 16, 0, 0);
      __builtin_amdgcn_global_load_lds((const AS1 void*)(Bbase + (long)i * 32 * ldb + k0),
                                       (AS3 void*)(Bs[b] + woff + i * 2048), 16, 0, 0);
    }
  };

  f32x4 acc[4][4] = {};

  stage(0, 0);
  int buf = 0;
  for (int k0 = 0; k0 < K; k0 += 64) {
    __syncthreads();                   // drains tile-k loads (issued 1 iter ago)
    if (k0 + 64 < K) stage(k0 + 64, buf ^ 1);
#pragma unroll
    for (int s = 0; s < 2; s++) {
      bf16x8 aF[4], bF[4];
#pragma unroll
      for (int i = 0; i < 4; i++) {
        const int r = wm + i * 16 + lm;
        aF[i] = *(const bf16x8*)&As[buf][r * 64 + (((s * 4 + qd) ^ (lm & 7)) << 3)];
      }
#pragma unroll
      for (int j = 0; j < 4; j++) {
        const int r = wn + j * 16 + lm;
        bF[j] = *(const bf16x8*)&Bs[buf][r * 64 + (((s * 4 + qd) ^ (lm & 7)) << 3)];
      }
#pragma unroll
      for (int i = 0; i < 4; i++)
#pragma unroll
        for (int j = 0; j < 4; j++)
          acc[i][j] = __builtin_amdgcn_mfma_f32_16x16x32_bf16(aF[i], bF[j], acc[i][j], 0, 0, 0);
    }
    buf ^= 1;
  }

#pragma unroll
  for (int i = 0; i < 4; i++) {
    const int row = m0 + wm + i * 16 + qd * 4;
#pragma unroll
    for (int j = 0; j < 4; j++) {
      const int col = n0 + wn + j * 16 + lm;
#pragma unroll
      for (int r = 0; r < 4; r++)
        C[(long)(row + r) * ldc + col] = (OutT)acc[i][j][r];
    }
  }
}

// ---------------------------------------------------------------------------
// Small-tile NT bf16 GEMM for the causal steps: tile 64x128, BK=64,
// 256 threads (wave w covers cols w*32..w*32+31, all 64 rows).
// DOUBLE-BUFFERED 48KB LDS -> 3 blocks/CU; causal grids supply 1088/1024
// active blocks (~4.25/CU). Measured equal to 128x128 dbuf on these steps
// (rounds 4 vs 7) — the occupancy-vs-AI trade is a wash; kept for lower
// tile-granularity imbalance.
//
// Same XOR-swizzled LDS layout (slot = q ^ (row&7)), measured conflict-free.
//
// causalHalf: skip block if bn > bm>>1    (S = QK^T lower-triangle tiles)
// kLimit64:   Keff = min(K, ((bm>>1)+1)*128), bm flipped heavy-first
//             (PV truncation; row-uniform within a 64-row tile and equal to
//              softmax's zero-filled kend -> no uninitialized P reads).
// ---------------------------------------------------------------------------
template <typename OutT>
__global__ __launch_bounds__(256)
void gemm_nt64(const bf16_t* __restrict__ A, const bf16_t* __restrict__ B,
               OutT* __restrict__ C, int K, int lda, int ldb, int ldc,
               long sA, long sB, long sC, int causalHalf, int kLimit64)
{
  int bm = blockIdx.y;
  const int bn = blockIdx.x;
  if (kLimit64) bm = gridDim.y - 1 - bm;   // heavy tiles dispatch first
  if (causalHalf && bn > (bm >> 1)) return;
  A += (long)blockIdx.z * sA;
  B += (long)blockIdx.z * sB;
  C += (long)blockIdx.z * sC;
  const int m0 = bm * 64, n0 = bn * 128;
  int Keff = K;
  if (kLimit64) { const int kl = ((bm >> 1) + 1) * 128; if (kl < Keff) Keff = kl; }

  __shared__ bf16_t As[2][64 * 64];    // 8KB each
  __shared__ bf16_t Bs[2][128 * 64];   // 16KB each  (48KB total)

  const int tid = threadIdx.x;
  const int wave = tid >> 6, lane = tid & 63;
  const int lm = lane & 15, qd = lane >> 4;
  const int wn = wave * 32;

  const int rowl = lane >> 3;           // 0..7
  const int q = (lane & 7) ^ rowl;      // swizzled chunk within row
  const bf16_t* Abase = A + (long)(m0 + wave * 8 + rowl) * lda + q * 8;
  const bf16_t* Bbase = B + (long)(n0 + wave * 8 + rowl) * ldb + q * 8;
  const int woff = wave * 512;          // wave-uniform LDS elem base

  auto stage = [&](int k0, int b) {
#pragma unroll
    for (int i = 0; i < 2; i++)
      __builtin_amdgcn_global_load_lds((const AS1 void*)(Abase + (long)i * 32 * lda + k0),
                                       (AS3 void*)(As[b] + woff + i * 2048), 16, 0, 0);
#pragma unroll
    for (int i = 0; i < 4; i++)
      __builtin_amdgcn_global_load_lds((const AS1 void*)(Bbase + (long)i * 32 * ldb + k0),
                                       (AS3 void*)(Bs[b] + woff + i * 2048), 16, 0, 0);
  };

  f32x4 acc[4][2] = {};

  stage(0, 0);
  int buf = 0;
  for (int k0 = 0; k0 < Keff; k0 += 64) {
    __syncthreads();                   // drains tile-k loads (issued 1 iter ago)
    if (k0 + 64 < Keff) stage(k0 + 64, buf ^ 1);
#pragma unroll
    for (int s = 0; s < 2; s++) {
      bf16x8 aF[4], bF[2];
#pragma unroll
      for (int i = 0; i < 4; i++) {
        const int r = i * 16 + lm;
        aF[i] = *(const bf16x8*)&As[buf][r * 64 + (((s * 4 + qd) ^ (lm & 7)) << 3)];
      }
#pragma unroll
      for (int j = 0; j < 2; j++) {
        const int r = wn + j * 16 + lm;
        bF[j] = *(const bf16x8*)&Bs[buf][r * 64 + (((s * 4 + qd) ^ (lm & 7)) << 3)];
      }
#pragma unroll
      for (int i = 0; i < 4; i++)
#pragma unroll
        for (int j = 0; j < 2; j++)
          acc[i][j] = __builtin_amdgcn_mfma_f32_16x16x32_bf16(aF[i], bF[j], acc[i][j], 0, 0, 0);
    }
    buf ^= 1;
  }

#pragma unroll
  for (int i = 0; i < 4; i++) {
    const int row = m0 + i * 16 + qd * 4;
#pragma unroll
    for (int j = 0; j < 2; j++) {
      const int col = n0 + wn + j * 16 + lm;
#pragma unroll
      for (int r = 0; r < 4; r++)
        C[(long)(row + r) * ldc + col] = (OutT)acc[i][j][r];
    }
  }
}

// ---------------------------------------------------------------------------
// Fused prep (ONE dispatch): blocks [0,8192) convert X fp32->bf16 (float4
// loads); blocks [8192, 8192+3072) transpose+convert Wq/Wk/Wv into
// WT[out][in] bf16 (32x32 tiles, 256 threads, 4 rows/thread). The 3072
// small transpose blocks backfill the cvt tail.
// ---------------------------------------------------------------------------
__global__ __launch_bounds__(256)
void prep(const float* __restrict__ X, bf16_t* __restrict__ Xb,
          const float* __restrict__ wq, const float* __restrict__ wk,
          const float* __restrict__ wv, bf16_t* __restrict__ WT)
{
  const int b = blockIdx.x;
  if (b < 8192) {                       // X -> bf16, 4 floats/thread
    const int i = b * 256 + threadIdx.x;
    const float4 f = ((const float4*)X)[i];
    bf16x4 o = {(bf16_t)f.x, (bf16_t)f.y, (bf16_t)f.z, (bf16_t)f.w};
    ((bf16x4*)Xb)[i] = o;
    return;
  }
  const int wid = b - 8192;             // 0..3071
  const int z = wid >> 10;              // which W
  const int t = wid & 1023;             // tile id, 32x32 grid of 32x32 tiles
  const int tix = t & 31, tiy = t >> 5; // tix: out-dim tile, tiy: in-dim tile
  const float* W = (z == 0) ? wq : (z == 1) ? wk : wv;
  bf16_t* O = WT + (long)z * 1024 * 1024;

  __shared__ float tile[32][33];
  const int x = threadIdx.x & 31, y0 = threadIdx.x >> 5;  // y0: 0..7
#pragma unroll
  for (int r = 0; r < 4; r++) {         // read: coalesced over out dim (x)
    const int y = y0 + r * 8;
    tile[y][x] = W[(long)(tiy * 32 + y) * 1024 + (tix * 32 + x)];
  }
  __syncthreads();
#pragma unroll
  for (int r = 0; r < 4; r++) {         // write: coalesced over in dim (x)
    const int y = y0 + r * 8;
    O[(long)(tix * 32 + y) * 1024 + (tiy * 32 + x)] = (bf16_t)tile[x][y];
  }
}

// ---------------------------------------------------------------------------
// In-place causal softmax over S rows (bf16, ld=2048). One block per row.
// logits = S/32; writes P = softmax, zeros above the diagonal.
// Loads only j <= t; stores only j < kend = ((t>>7)+1)*128 — beyond kend P
// is never read by the PV GEMM (Keff stops there); [t+1, kend) gets zeros.
// ---------------------------------------------------------------------------
__global__ __launch_bounds__(256)
void softmax_causal(bf16_t* __restrict__ S)
{
  const int row = blockIdx.x;
  const int t = row & 2047;
  const int kend = ((t >> 7) + 1) << 7;
  bf16_t* Sr = S + (long)row * 2048;
  const int base = threadIdx.x * 8;

  uint4 u = {0, 0, 0, 0};
  if (base <= t) u = *(const uint4*)(Sr + base);
  const unsigned short* up = (const unsigned short*)&u;
  float v[8];
  float m = -3.0e38f;
#pragma unroll
  for (int j = 0; j < 8; j++) {
    const float x = __uint_as_float(((unsigned)up[j]) << 16);  // bf16 bits -> f32
    v[j] = (base + j <= t) ? x : -3.0e38f;
    m = fmaxf(m, v[j]);
  }
#pragma unroll
  for (int off = 32; off > 0; off >>= 1) m = fmaxf(m, __shfl_xor(m, off));
  __shared__ float redm[4], redl[4];
  const int wave = threadIdx.x >> 6, lane = threadIdx.x & 63;
  if (lane == 0) redm[wave] = m;
  __syncthreads();
  m = fmaxf(fmaxf(redm[0], redm[1]), fmaxf(redm[2], redm[3]));

  float p[8], l = 0.f;
#pragma unroll
  for (int j = 0; j < 8; j++) {
    p[j] = (base + j <= t) ? __expf((v[j] - m) * 0.03125f) : 0.f;
    l += p[j];
  }
#pragma unroll
  for (int off = 32; off > 0; off >>= 1) l += __shfl_xor(l, off);
  if (lane == 0) redl[wave] = l;
  __syncthreads();
  l = (redl[0] + redl[1]) + (redl[2] + redl[3]);
  const float rl = 1.0f / l;

  if (base < kend) {
    uint4 w;
    unsigned* wp = (unsigned*)&w;
#pragma unroll
    for (int h = 0; h < 4; h++) {
      bf16_t a = (bf16_t)(p[2 * h] * rl);
      bf16_t b = (bf16_t)(p[2 * h + 1] * rl);
      wp[h] = (unsigned)__builtin_bit_cast(unsigned short, a) |
              ((unsigned)__builtin_bit_cast(unsigned short, b) << 16);
    }
    *(uint4*)(Sr + base) = w;
  }
}

// ---------------------------------------------------------------------------
extern "C" void kernel_launch(void* const* d_in, const int* in_sizes, int n_in,
                              void* d_out, int out_size, void* d_ws, size_t ws_size,
                              hipStream_t stream)
{
  const float* X  = (const float*)d_in[0];  // [4,2048,1024]
  const float* Wq = (const float*)d_in[1];  // [1024,1024] (in,out)
  const float* Wk = (const float*)d_in[2];
  const float* Wv = (const float*)d_in[3];
  float* out = (float*)d_out;               // [4,2048,1024]

  // workspace layout (bytes): QK 33.5M | VT 16.8M | WT 6.3M | {Xb 16.8M / S 33.5M overlap}
  char* p = (char*)d_ws;
  bf16_t* QK = (bf16_t*)p;  p += (size_t)8192 * 2048 * 2;   // [8192, 2048]  Q|K
  bf16_t* VT = (bf16_t*)p;  p += (size_t)1024 * 8192 * 2;   // [1024, 8192]  V^T
  bf16_t* WT = (bf16_t*)p;  p += (size_t)3072 * 1024 * 2;   // [3072, 1024]  Wq^T|Wk^T|Wv^T
  bf16_t* Xb = (bf16_t*)p;                                  // [8192, 1024]  (dead before S)
  bf16_t* S  = (bf16_t*)p;                                  // [4][2048,2048] scores->P

  // 1) fused prep: X -> bf16  +  W -> WT (bf16, transposed)   (one dispatch)
  prep<<<8192 + 3072, 256, 0, stream>>>(X, Xb, Wq, Wk, Wv, WT);
  // 2) QK = Xb @ [Wq|Wk]   M=8192 N=2048 K=1024   (1024 blocks, dbuf)
  gemm_nt<bf16_t><<<dim3(16, 64), 256, 0, stream>>>(
      Xb, WT, QK, 1024, 1024, 1024, 2048);
  // 3) VT = WvT @ Xb^T     M=1024 N=8192 K=1024   (512 blocks, dbuf)
  gemm_nt<bf16_t><<<dim3(64, 8), 256, 0, stream>>>(
      WT + (long)2048 * 1024, Xb, VT, 1024, 1024, 1024, 8192);
  // 4) S = Q @ K^T per batch, 64-row tiles, lower-tri only (1088 active), dbuf
  gemm_nt64<bf16_t><<<dim3(16, 32, 4), 256, 0, stream>>>(
      QK, QK + 1024, S, 1024, 2048, 2048, 2048,
      (long)2048 * 2048, (long)2048 * 2048, (long)2048 * 2048, 1, 0);
  // 5) in-place causal softmax (truncated IO)
  softmax_causal<<<8192, 256, 0, stream>>>(S);
  // 6) O = P @ V (NT vs V^T), 64-row tiles, K truncated at diagonal, dbuf
  gemm_nt64<float><<<dim3(8, 32, 4), 256, 0, stream>>>(
      S, VT, out, 2048, 2048, 8192, 1024,
      (long)2048 * 2048, 2048, (long)2048 * 1024, 0, 1);
}